// Round 17
// baseline (35.512 us; speedup 1.0000x reference)
//
#include <hip/hip_runtime.h>
#include <hip/hip_bf16.h>

#define NUM_HEADS 16
#define HEAD_DIM  64
#define HD        1024   // NUM_HEADS*HEAD_DIM
#define SEQL      1024
#define NTILE     16     // 64-kv tiles per sequence
#define TILE_E    4096   // elements per 64x64 bf16 tile (8 KB)
#define HSTRIDE   (64 * TILE_E)          // 64 tiles per head
#define VT_OFF    (NUM_HEADS * HSTRIDE)  // V-fragment array offset in ws (elems)
#define FIXED_M   12.0f                  // fixed log2-domain shift (max score ~8 sigma)
#define QK_SCALE  0.1803368801111204f    // 0.125 * log2(e), folded into K during prep

typedef __bf16 bf16x8 __attribute__((ext_vector_type(8)));
typedef float  f32x4  __attribute__((ext_vector_type(4)));

#define MFMA16(A, B, C) __builtin_amdgcn_mfma_f32_16x16x32_bf16((A), (B), (C), 0, 0, 0)
#define GLOAD_LDS16(gp, lp) \
  __builtin_amdgcn_global_load_lds((const __attribute__((address_space(1))) void*)(gp), \
                                   (__attribute__((address_space(3))) void*)(lp), 16, 0, 0)

// ---------------- prep: fp32 K,V -> bf16 PER-FRAGMENT-CONTIGUOUS tiles ----------------
// K tile (pre-scaled by QK_SCALE): fragment f = t*2+c contiguous 1KB;
//   lane l=(g,a): K[kv0+16t+a][32c+8g..+8] * QK_SCALE
// V tile: fragment f = dt*2+cc contiguous 1KB; lane l=(g,a): elem e =
//         V[kv0 + 32cc+16(e>>2)+4g+(e&3)][16dt+a]
__global__ __launch_bounds__(256)
void prep_kernel(const float* __restrict__ K, const float* __restrict__ V,
                 __bf16* __restrict__ ws)
{
    __shared__ __bf16 v_s[64][72];
    const int tid  = threadIdx.x;
    const int bx   = blockIdx.x;                 // 0..1023
    const int orig = (bx & 7) * 128 + (bx >> 3); // XCD x owns orig in [x*128, x*128+128)
    const int h    = orig >> 6;
    const int tile = orig & 63;                  // seq*16 + it
    const int kv0  = tile * 64;
    __bf16* kb = ws + (size_t)h * HSTRIDE + (size_t)tile * TILE_E;
    __bf16* vt = ws + VT_OFF + (size_t)h * HSTRIDE + (size_t)tile * TILE_E;

    #pragma unroll
    for (int i = 0; i < 2; ++i) {
        const int c2 = tid + 256 * i;      // chunk id 0..511
        const int f  = c2 >> 6;
        const int l  = c2 & 63;
        const int g  = l >> 4, aa = l & 15;
        const int t  = f >> 1, cc = f & 1;
        const int r  = 16 * t + aa;
        const int d0 = 32 * cc + 8 * g;

        const float* kp = K + (size_t)(kv0 + r) * HD + h * HEAD_DIM + d0;
        float4 f0 = *(const float4*)kp, f1 = *(const float4*)(kp + 4);
        bf16x8 u = {(__bf16)(f0.x * QK_SCALE), (__bf16)(f0.y * QK_SCALE),
                    (__bf16)(f0.z * QK_SCALE), (__bf16)(f0.w * QK_SCALE),
                    (__bf16)(f1.x * QK_SCALE), (__bf16)(f1.y * QK_SCALE),
                    (__bf16)(f1.z * QK_SCALE), (__bf16)(f1.w * QK_SCALE)};
        *reinterpret_cast<bf16x8*>(kb + f * 512 + l * 8) = u;

        const float* vp = V + (size_t)(kv0 + r) * HD + h * HEAD_DIM + d0;
        float4 g0 = *(const float4*)vp, g1 = *(const float4*)(vp + 4);
        bf16x8 w = {(__bf16)g0.x, (__bf16)g0.y, (__bf16)g0.z, (__bf16)g0.w,
                    (__bf16)g1.x, (__bf16)g1.y, (__bf16)g1.z, (__bf16)g1.w};
        *reinterpret_cast<bf16x8*>(&v_s[r][d0]) = w;
    }
    __syncthreads();
    #pragma unroll
    for (int i = 0; i < 2; ++i) {
        const int c2 = tid + 256 * i;
        const int f  = c2 >> 6;
        const int l  = c2 & 63;
        const int g  = l >> 4, aa = l & 15;
        const int dt = f >> 1, cc = f & 1;
        const int d  = 16 * dt + aa;
        bf16x8 w;
        #pragma unroll
        for (int e = 0; e < 8; ++e) {
            const int kvl = 32 * cc + ((e >> 2) << 4) + 4 * g + (e & 3);
            w[e] = v_s[kvl][d];
        }
        *reinterpret_cast<bf16x8*>(vt + f * 512 + l * 8) = w;
    }
}

// --- attention: K via LDS (4x8KB buffers, counted vmcnt), V DIRECT from ws (L1/L2),
// --- cross-tile pipeline: PV(t-1) under K-reads(t); V(t) prefetch spans the barrier ---
__global__ __launch_bounds__(256, 2)
void fattn17_kernel(const float* __restrict__ Q, const __bf16* __restrict__ ws,
                    float* __restrict__ O)
{
    __shared__ __bf16 buf[4][TILE_E];   // 4 x 8 KB: K fragments only

    const int tid  = threadIdx.x;
    const int lane = tid & 63;
    const int wave = tid >> 6;
    const int g    = lane >> 4;
    const int a    = lane & 15;

    // 512 blocks; bijective XCD chunking: XCD x gets orig in [x*64, x*64+64)
    const int b     = blockIdx.x;
    const int orig  = (b & 7) * 64 + (b >> 3);
    const int group = orig >> 3;          // h*4 + seq
    const int qb    = orig & 7;
    const int h     = group >> 2;
    const int seq   = group & 3;
    const int q0    = seq * SEQL + qb * 128;   // block: 128 q rows; wave: 32

    const __bf16* kb_base = ws + (size_t)h * HSTRIDE + (size_t)seq * NTILE * TILE_E;
    const __bf16* vt_base = ws + VT_OFF + (size_t)h * HSTRIDE + (size_t)seq * NTILE * TILE_E;

    // Q fragments for 2 q-subtiles (scale folded into K by prep)
    bf16x8 qf[2][2];
    #pragma unroll
    for (int u = 0; u < 2; ++u) {
        const float* qp = Q + (size_t)(q0 + wave * 32 + u * 16 + a) * HD + h * HEAD_DIM + g * 8;
        #pragma unroll
        for (int c = 0; c < 2; ++c) {
            float4 f0 = *reinterpret_cast<const float4*>(qp + 32 * c);
            float4 f1 = *reinterpret_cast<const float4*>(qp + 32 * c + 4);
            qf[u][c][0] = (__bf16)f0.x; qf[u][c][1] = (__bf16)f0.y;
            qf[u][c][2] = (__bf16)f0.z; qf[u][c][3] = (__bf16)f0.w;
            qf[u][c][4] = (__bf16)f1.x; qf[u][c][5] = (__bf16)f1.y;
            qf[u][c][6] = (__bf16)f1.z; qf[u][c][7] = (__bf16)f1.w;
        }
    }

    f32x4 o_acc[2][4];
    #pragma unroll
    for (int u = 0; u < 2; ++u)
        #pragma unroll
        for (int dt = 0; dt < 4; ++dt) o_acc[u][dt] = (f32x4){0.f, 0.f, 0.f, 0.f};
    f32x4 l_acc[2] = {(f32x4){0.f, 0.f, 0.f, 0.f}, (f32x4){0.f, 0.f, 0.f, 0.f}};

    bf16x8 ones;
    #pragma unroll
    for (int e = 0; e < 8; ++e) ones[e] = (__bf16)1.0f;

    const f32x4 minit = (f32x4){-FIXED_M, -FIXED_M, -FIXED_M, -FIXED_M};
    const int lb    = lane * 16;   // byte slot within a 1KB fragment
    const int loff  = lane * 8;    // elem slot within a 512-elem fragment
    const int stid8 = tid * 8;

    // K-only stage: 2 gload_lds per wave (vmcnt += 2)
    auto stage = [&](const int bi, int t) {
        const __bf16* ks = kb_base + (size_t)t * TILE_E + stid8;
        GLOAD_LDS16(ks,        &buf[bi][stid8]);
        GLOAD_LDS16(ks + 2048, &buf[bi][2048 + stid8]);
    };

    // PV cluster for tile t-1 (register-only MFMA; compiler's counted vmcnt wait
    // for vfP precedes the first use — V prefetch drains here, not at a barrier)
    auto pv = [&](const bf16x8 (&pfP)[2][2], const bf16x8 (&vfP)[8]) {
        __builtin_amdgcn_s_setprio(1);
        l_acc[0] = MFMA16(pfP[0][0], ones, l_acc[0]);
        l_acc[0] = MFMA16(pfP[0][1], ones, l_acc[0]);
        l_acc[1] = MFMA16(pfP[1][0], ones, l_acc[1]);
        l_acc[1] = MFMA16(pfP[1][1], ones, l_acc[1]);
        #pragma unroll
        for (int dt = 0; dt < 4; ++dt)
            #pragma unroll
            for (int u = 0; u < 2; ++u) {
                o_acc[u][dt] = MFMA16(pfP[u][0], vfP[2 * dt],     o_acc[u][dt]);
                o_acc[u][dt] = MFMA16(pfP[u][1], vfP[2 * dt + 1], o_acc[u][dt]);
            }
        __builtin_amdgcn_s_setprio(0);
    };

    bf16x8 pfA[2][2], pfB[2][2];
    bf16x8 vfA[8], vfB[8];

    stage(0, 0);
    stage(1, 1);   // 4 vm outstanding

    // Manual vmcnt covers stage(t) exactly (in-order retire; N = #VM ops issued after
    // stage(t)'s last load): t=0: stage(1)=2. t=1: vf(0)8+stage(2)2=10.
    // 2<=t<=14: vf(t-2)8+stage(t+1)2+vf(t-1)8=18. t=15: vf(13)8+vf(14)8=16.
    auto body = [&](int t, bf16x8 (&pfC)[2][2], bf16x8 (&vfC)[8],
                    bf16x8 (&pfP)[2][2], bf16x8 (&vfP)[8]) {
        if      (t == 0)  asm volatile("s_waitcnt vmcnt(2)"  ::: "memory");
        else if (t == 1)  asm volatile("s_waitcnt vmcnt(10)" ::: "memory");
        else if (t == 15) asm volatile("s_waitcnt vmcnt(16)" ::: "memory");
        else              asm volatile("s_waitcnt vmcnt(18)" ::: "memory");
        __builtin_amdgcn_sched_barrier(0);
        __builtin_amdgcn_s_barrier();
        __builtin_amdgcn_sched_barrier(0);   // no ds_read hoisted above the barrier
        if (t <= 13) stage((t + 2) & 3, t + 2);

        const char* kc = (const char*)&buf[t & 3][0];
        const __bf16* vtile = vt_base + (size_t)t * TILE_E;

        // K fragment reads — compiler emits counted lgkm waits for the MFMA deps
        bf16x8 kf[8];
        #pragma unroll
        for (int f = 0; f < 8; ++f)
            kf[f] = *reinterpret_cast<const bf16x8*>(kc + f * 1024 + lb);

        if (t > 0) pv(pfP, vfP);   // MFMA pipe fills K ds_read latency; drains vf(t-1)

        // ---- QK^T (swapped): s[u][q4][r] = S^T[kv=16q4+4g+r][q=a] - FIXED_M ----
        f32x4 s[2][4];
        __builtin_amdgcn_s_setprio(1);
        #pragma unroll
        for (int q4 = 0; q4 < 4; ++q4) {
            s[0][q4] = MFMA16(kf[2 * q4],     qf[0][0], minit);
            s[0][q4] = MFMA16(kf[2 * q4 + 1], qf[0][1], s[0][q4]);
            s[1][q4] = MFMA16(kf[2 * q4],     qf[1][0], minit);
            s[1][q4] = MFMA16(kf[2 * q4 + 1], qf[1][1], s[1][q4]);
        }
        __builtin_amdgcn_s_setprio(0);

        // V fragments DIRECT from ws (coalesced 1KB spans; L1 serves waves 2..4).
        // True async prefetch: consumed by pv() in body t+1 via compiler-counted vmcnt.
        #pragma unroll
        for (int f = 0; f < 8; ++f)
            vfC[f] = *reinterpret_cast<const bf16x8*>(vtile + f * 512 + loff);

        // fixed-shift softmax: pf[u][c] elem bb -> kv = 32c + 16(bb>>2) + 4g + (bb&3)
        #pragma unroll
        for (int u = 0; u < 2; ++u)
            #pragma unroll
            for (int c = 0; c < 2; ++c)
                #pragma unroll
                for (int bb = 0; bb < 8; ++bb)
                    pfC[u][c][bb] = (__bf16)__builtin_amdgcn_exp2f(s[u][2 * c + (bb >> 2)][bb & 3]);
    };

    #pragma unroll
    for (int tt = 0; tt < 8; ++tt) {
        body(2 * tt,     pfA, vfA, pfB, vfB);
        body(2 * tt + 1, pfB, vfB, pfA, vfA);
    }
    pv(pfB, vfB);   // PV(15); compiler waits vf(15)

    // ---- epilogue: O rows q = wave*32 + u*16 + 4g + r, cols d = 16dt + a ----
    #pragma unroll
    for (int u = 0; u < 2; ++u)
        #pragma unroll
        for (int r = 0; r < 4; ++r) {
            const float inv = 1.0f / l_acc[u][r];
            float* op = O + (size_t)(q0 + wave * 32 + u * 16 + 4 * g + r) * HD + h * HEAD_DIM + a;
            #pragma unroll
            for (int dt = 0; dt < 4; ++dt)
                op[16 * dt] = o_acc[u][dt][r] * inv;
        }
}

extern "C" void kernel_launch(void* const* d_in, const int* in_sizes, int n_in,
                              void* d_out, int out_size, void* d_ws, size_t ws_size,
                              hipStream_t stream) {
    const float* q = (const float*)d_in[0];
    const float* k = (const float*)d_in[1];
    const float* v = (const float*)d_in[2];
    float* out = (float*)d_out;
    __bf16* ws = (__bf16*)d_ws;   // 16 MB: 8 MB K-fragments (pre-scaled) + 8 MB V-fragments

    prep_kernel<<<1024, 256, 0, stream>>>(k, v, ws);
    fattn17_kernel<<<512, 256, 0, stream>>>(q, ws, out);
}

// Round 18
// 33.947 us; speedup vs baseline: 1.0461x; 1.0461x over previous
//
#include <hip/hip_runtime.h>
#include <hip/hip_bf16.h>

#define NUM_HEADS 16
#define HEAD_DIM  64
#define HD        1024   // NUM_HEADS*HEAD_DIM
#define SEQL      1024
#define NTILE     16     // 64-kv tiles per sequence
#define TILE_E    4096   // elements per 64x64 bf16 tile (8 KB)
#define HSTRIDE   (64 * TILE_E)          // 64 tiles per head
#define VT_OFF    (NUM_HEADS * HSTRIDE)  // V-fragment array offset in ws (elems)
#define FIXED_M   12.0f                  // fixed log2-domain shift (max score ~8 sigma)
#define QK_SCALE  0.1803368801111204f    // 0.125 * log2(e), folded into K during prep

typedef __bf16 bf16x8 __attribute__((ext_vector_type(8)));
typedef float  f32x4  __attribute__((ext_vector_type(4)));

#define MFMA16(A, B, C) __builtin_amdgcn_mfma_f32_16x16x32_bf16((A), (B), (C), 0, 0, 0)
#define GLOAD_LDS16(gp, lp) \
  __builtin_amdgcn_global_load_lds((const __attribute__((address_space(1))) void*)(gp), \
                                   (__attribute__((address_space(3))) void*)(lp), 16, 0, 0)

// ---------------- prep: fp32 K,V -> bf16 PER-FRAGMENT-CONTIGUOUS tiles ----------------
// K tile (pre-scaled by QK_SCALE): fragment f = t*2+c contiguous 1KB;
//   lane l=(g,a): K[kv0+16t+a][32c+8g..+8] * QK_SCALE
// V tile: fragment f = dt*2+cc contiguous 1KB; lane l=(g,a): elem e =
//         V[kv0 + 32cc+16(e>>2)+4g+(e&3)][16dt+a]
__global__ __launch_bounds__(256)
void prep_kernel(const float* __restrict__ K, const float* __restrict__ V,
                 __bf16* __restrict__ ws)
{
    __shared__ __bf16 v_s[64][72];
    const int tid  = threadIdx.x;
    const int bx   = blockIdx.x;                 // 0..1023
    const int orig = (bx & 7) * 128 + (bx >> 3); // XCD x owns orig in [x*128, x*128+128)
    const int h    = orig >> 6;
    const int tile = orig & 63;                  // seq*16 + it
    const int kv0  = tile * 64;
    __bf16* kb = ws + (size_t)h * HSTRIDE + (size_t)tile * TILE_E;
    __bf16* vt = ws + VT_OFF + (size_t)h * HSTRIDE + (size_t)tile * TILE_E;

    #pragma unroll
    for (int i = 0; i < 2; ++i) {
        const int c2 = tid + 256 * i;      // chunk id 0..511
        const int f  = c2 >> 6;
        const int l  = c2 & 63;
        const int g  = l >> 4, aa = l & 15;
        const int t  = f >> 1, cc = f & 1;
        const int r  = 16 * t + aa;
        const int d0 = 32 * cc + 8 * g;

        const float* kp = K + (size_t)(kv0 + r) * HD + h * HEAD_DIM + d0;
        float4 f0 = *(const float4*)kp, f1 = *(const float4*)(kp + 4);
        bf16x8 u = {(__bf16)(f0.x * QK_SCALE), (__bf16)(f0.y * QK_SCALE),
                    (__bf16)(f0.z * QK_SCALE), (__bf16)(f0.w * QK_SCALE),
                    (__bf16)(f1.x * QK_SCALE), (__bf16)(f1.y * QK_SCALE),
                    (__bf16)(f1.z * QK_SCALE), (__bf16)(f1.w * QK_SCALE)};
        *reinterpret_cast<bf16x8*>(kb + f * 512 + l * 8) = u;

        const float* vp = V + (size_t)(kv0 + r) * HD + h * HEAD_DIM + d0;
        float4 g0 = *(const float4*)vp, g1 = *(const float4*)(vp + 4);
        bf16x8 w = {(__bf16)g0.x, (__bf16)g0.y, (__bf16)g0.z, (__bf16)g0.w,
                    (__bf16)g1.x, (__bf16)g1.y, (__bf16)g1.z, (__bf16)g1.w};
        *reinterpret_cast<bf16x8*>(&v_s[r][d0]) = w;
    }
    __syncthreads();
    #pragma unroll
    for (int i = 0; i < 2; ++i) {
        const int c2 = tid + 256 * i;
        const int f  = c2 >> 6;
        const int l  = c2 & 63;
        const int g  = l >> 4, aa = l & 15;
        const int dt = f >> 1, cc = f & 1;
        const int d  = 16 * dt + aa;
        bf16x8 w;
        #pragma unroll
        for (int e = 0; e < 8; ++e) {
            const int kvl = 32 * cc + ((e >> 2) << 4) + 4 * g + (e & 3);
            w[e] = v_s[kvl][d];
        }
        *reinterpret_cast<bf16x8*>(vt + f * 512 + l * 8) = w;
    }
}

// --- attention: FULL K (128 KB) resident in dynamic LDS, staged once; ZERO main-loop
// --- barriers; V direct from ws (L1/L2); cross-tile PV(t-1) pipeline; waves drift freely.
__global__ __launch_bounds__(512, 2)
void fattn18_kernel(const float* __restrict__ Q, const __bf16* __restrict__ ws,
                    float* __restrict__ O)
{
    extern __shared__ __bf16 kres[];   // NTILE * TILE_E = 128 KB, K fragments, read-only

    const int tid  = threadIdx.x;
    const int lane = tid & 63;
    const int wave = tid >> 6;          // 0..7
    const int g    = lane >> 4;
    const int a    = lane & 15;

    // 256 blocks (1/CU); bijective XCD chunking: XCD x gets orig in [x*32, x*32+32)
    // -> heads {2x, 2x+1}, matching prep's placement
    const int b     = blockIdx.x;
    const int orig  = (b & 7) * 32 + (b >> 3);
    const int group = orig >> 2;          // h*4 + seq
    const int qb    = orig & 3;           // q-block within sequence (256 rows)
    const int h     = group >> 2;
    const int seq   = group & 3;
    const int q0    = seq * SEQL + qb * 256;   // block: 256 q rows; wave: 32

    const __bf16* kb_base = ws + (size_t)h * HSTRIDE + (size_t)seq * NTILE * TILE_E;
    const __bf16* vt_base = ws + VT_OFF + (size_t)h * HSTRIDE + (size_t)seq * NTILE * TILE_E;

    // Q fragments for 2 q-subtiles (scale folded into K by prep)
    bf16x8 qf[2][2];
    #pragma unroll
    for (int u = 0; u < 2; ++u) {
        const float* qp = Q + (size_t)(q0 + wave * 32 + u * 16 + a) * HD + h * HEAD_DIM + g * 8;
        #pragma unroll
        for (int c = 0; c < 2; ++c) {
            float4 f0 = *reinterpret_cast<const float4*>(qp + 32 * c);
            float4 f1 = *reinterpret_cast<const float4*>(qp + 32 * c + 4);
            qf[u][c][0] = (__bf16)f0.x; qf[u][c][1] = (__bf16)f0.y;
            qf[u][c][2] = (__bf16)f0.z; qf[u][c][3] = (__bf16)f0.w;
            qf[u][c][4] = (__bf16)f1.x; qf[u][c][5] = (__bf16)f1.y;
            qf[u][c][6] = (__bf16)f1.z; qf[u][c][7] = (__bf16)f1.w;
        }
    }

    // ---- prologue: stage the ENTIRE K for this (h,seq) into LDS (one barrier total) ----
    #pragma unroll
    for (int t = 0; t < NTILE; ++t)
        GLOAD_LDS16(kb_base + (size_t)t * TILE_E + tid * 8, &kres[t * TILE_E + tid * 8]);
    asm volatile("s_waitcnt vmcnt(0)" ::: "memory");
    __syncthreads();   // K resident & visible; no further barriers

    f32x4 o_acc[2][4];
    #pragma unroll
    for (int u = 0; u < 2; ++u)
        #pragma unroll
        for (int dt = 0; dt < 4; ++dt) o_acc[u][dt] = (f32x4){0.f, 0.f, 0.f, 0.f};
    f32x4 l_acc[2] = {(f32x4){0.f, 0.f, 0.f, 0.f}, (f32x4){0.f, 0.f, 0.f, 0.f}};

    bf16x8 ones;
    #pragma unroll
    for (int e = 0; e < 8; ++e) ones[e] = (__bf16)1.0f;

    const f32x4 minit = (f32x4){-FIXED_M, -FIXED_M, -FIXED_M, -FIXED_M};
    const int lb   = lane * 16;   // byte slot within a 1KB fragment
    const int loff = lane * 8;    // elem slot within a 512-elem fragment

    // PV cluster for tile t-1 (register-only MFMA; compiler's counted vmcnt wait
    // drains the vfP prefetch right before first use)
    auto pv = [&](const bf16x8 (&pfP)[2][2], const bf16x8 (&vfP)[8]) {
        __builtin_amdgcn_s_setprio(1);
        l_acc[0] = MFMA16(pfP[0][0], ones, l_acc[0]);
        l_acc[0] = MFMA16(pfP[0][1], ones, l_acc[0]);
        l_acc[1] = MFMA16(pfP[1][0], ones, l_acc[1]);
        l_acc[1] = MFMA16(pfP[1][1], ones, l_acc[1]);
        #pragma unroll
        for (int dt = 0; dt < 4; ++dt)
            #pragma unroll
            for (int u = 0; u < 2; ++u) {
                o_acc[u][dt] = MFMA16(pfP[u][0], vfP[2 * dt],     o_acc[u][dt]);
                o_acc[u][dt] = MFMA16(pfP[u][1], vfP[2 * dt + 1], o_acc[u][dt]);
            }
        __builtin_amdgcn_s_setprio(0);
    };

    bf16x8 pfA[2][2], pfB[2][2];
    bf16x8 vfA[8], vfB[8];

    // body(t): K-reads(t) from resident LDS || PV(t-1) -> QK(t) -> V-prefetch(t) || exp(t)
    auto body = [&](int t, bf16x8 (&pfC)[2][2], bf16x8 (&vfC)[8],
                    bf16x8 (&pfP)[2][2], bf16x8 (&vfP)[8]) {
        const char* kc = (const char*)kres + t * 8192;
        const __bf16* vtile = vt_base + (size_t)t * TILE_E;

        bf16x8 kf[8];
        #pragma unroll
        for (int f = 0; f < 8; ++f)
            kf[f] = *reinterpret_cast<const bf16x8*>(kc + f * 1024 + lb);

        if (t > 0) pv(pfP, vfP);   // MFMA pipe fills K ds_read latency; drains vf(t-1)

        // ---- QK^T (swapped): s[u][q4][r] = S^T[kv=16q4+4g+r][q=a] - FIXED_M ----
        f32x4 s[2][4];
        __builtin_amdgcn_s_setprio(1);
        #pragma unroll
        for (int q4 = 0; q4 < 4; ++q4) {
            s[0][q4] = MFMA16(kf[2 * q4],     qf[0][0], minit);
            s[0][q4] = MFMA16(kf[2 * q4 + 1], qf[0][1], s[0][q4]);
            s[1][q4] = MFMA16(kf[2 * q4],     qf[1][0], minit);
            s[1][q4] = MFMA16(kf[2 * q4 + 1], qf[1][1], s[1][q4]);
        }
        __builtin_amdgcn_s_setprio(0);

        // V fragments direct from ws (coalesced 1KB spans; L1 serves trailing waves).
        // Consumed by pv() in body t+1 via compiler-counted vmcnt — true async prefetch.
        #pragma unroll
        for (int f = 0; f < 8; ++f)
            vfC[f] = *reinterpret_cast<const bf16x8*>(vtile + f * 512 + loff);

        // fixed-shift softmax: pf[u][c] elem bb -> kv = 32c + 16(bb>>2) + 4g + (bb&3)
        #pragma unroll
        for (int u = 0; u < 2; ++u)
            #pragma unroll
            for (int c = 0; c < 2; ++c)
                #pragma unroll
                for (int bb = 0; bb < 8; ++bb)
                    pfC[u][c][bb] = (__bf16)__builtin_amdgcn_exp2f(s[u][2 * c + (bb >> 2)][bb & 3]);
    };

    #pragma unroll
    for (int tt = 0; tt < 8; ++tt) {
        body(2 * tt,     pfA, vfA, pfB, vfB);
        body(2 * tt + 1, pfB, vfB, pfA, vfA);
    }
    pv(pfB, vfB);   // PV(15); compiler waits vf(15)

    // ---- epilogue: O rows q = wave*32 + u*16 + 4g + r, cols d = 16dt + a ----
    #pragma unroll
    for (int u = 0; u < 2; ++u)
        #pragma unroll
        for (int r = 0; r < 4; ++r) {
            const float inv = 1.0f / l_acc[u][r];
            float* op = O + (size_t)(q0 + wave * 32 + u * 16 + 4 * g + r) * HD + h * HEAD_DIM + a;
            #pragma unroll
            for (int dt = 0; dt < 4; ++dt)
                op[16 * dt] = o_acc[u][dt][r] * inv;
        }
}

extern "C" void kernel_launch(void* const* d_in, const int* in_sizes, int n_in,
                              void* d_out, int out_size, void* d_ws, size_t ws_size,
                              hipStream_t stream) {
    const float* q = (const float*)d_in[0];
    const float* k = (const float*)d_in[1];
    const float* v = (const float*)d_in[2];
    float* out = (float*)d_out;
    __bf16* ws = (__bf16*)d_ws;   // 16 MB: 8 MB K-fragments (pre-scaled) + 8 MB V-fragments

    // allow 128 KB dynamic LDS (idempotent, deterministic; not a stream op)
    hipFuncSetAttribute((const void*)fattn18_kernel,
                        hipFuncAttributeMaxDynamicSharedMemorySize, NTILE * TILE_E * 2);

    prep_kernel<<<1024, 256, 0, stream>>>(k, v, ws);
    fattn18_kernel<<<256, 512, NTILE * TILE_E * 2, stream>>>(q, ws, out);
}

// Round 19
// 33.468 us; speedup vs baseline: 1.0611x; 1.0143x over previous
//
#include <hip/hip_runtime.h>
#include <hip/hip_bf16.h>

#define NUM_HEADS 16
#define HEAD_DIM  64
#define HD        1024   // NUM_HEADS*HEAD_DIM
#define SEQL      1024
#define NTILE     16     // 64-kv tiles per sequence
#define TILE_E    4096   // elements per 64x64 bf16 tile (8 KB)
#define HSTRIDE   (64 * TILE_E)          // 64 tiles per head
#define VT_OFF    (NUM_HEADS * HSTRIDE)  // V-fragment array offset in ws (elems)
#define FIXED_M   12.0f                  // fixed log2-domain shift (max score ~8 sigma)
#define QK_SCALE  0.1803368801111204f    // 0.125 * log2(e), folded into K during prep

typedef __bf16 bf16x8 __attribute__((ext_vector_type(8)));
typedef float  f32x4  __attribute__((ext_vector_type(4)));

#define MFMA16(A, B, C) __builtin_amdgcn_mfma_f32_16x16x32_bf16((A), (B), (C), 0, 0, 0)
#define GLOAD_LDS16(gp, lp) \
  __builtin_amdgcn_global_load_lds((const __attribute__((address_space(1))) void*)(gp), \
                                   (__attribute__((address_space(3))) void*)(lp), 16, 0, 0)

// ---------------- prep: fp32 K,V -> bf16 PER-FRAGMENT-CONTIGUOUS tiles ----------------
// K tile (pre-scaled by QK_SCALE): fragment f = t*2+c contiguous 1KB;
//   lane l=(g,a): K[kv0+16t+a][32c+8g..+8] * QK_SCALE
// V tile: fragment f = dt*2+cc contiguous 1KB; lane l=(g,a): elem e =
//         V[kv0 + 32cc+16(e>>2)+4g+(e&3)][16dt+a]
__global__ __launch_bounds__(256)
void prep_kernel(const float* __restrict__ K, const float* __restrict__ V,
                 __bf16* __restrict__ ws)
{
    __shared__ __bf16 v_s[64][72];
    const int tid  = threadIdx.x;
    const int bx   = blockIdx.x;                 // 0..1023
    const int orig = (bx & 7) * 128 + (bx >> 3); // XCD x owns orig in [x*128, x*128+128)
    const int h    = orig >> 6;
    const int tile = orig & 63;                  // seq*16 + it
    const int kv0  = tile * 64;
    __bf16* kb = ws + (size_t)h * HSTRIDE + (size_t)tile * TILE_E;
    __bf16* vt = ws + VT_OFF + (size_t)h * HSTRIDE + (size_t)tile * TILE_E;

    #pragma unroll
    for (int i = 0; i < 2; ++i) {
        const int c2 = tid + 256 * i;      // chunk id 0..511
        const int f  = c2 >> 6;
        const int l  = c2 & 63;
        const int g  = l >> 4, aa = l & 15;
        const int t  = f >> 1, cc = f & 1;
        const int r  = 16 * t + aa;
        const int d0 = 32 * cc + 8 * g;

        const float* kp = K + (size_t)(kv0 + r) * HD + h * HEAD_DIM + d0;
        float4 f0 = *(const float4*)kp, f1 = *(const float4*)(kp + 4);
        bf16x8 u = {(__bf16)(f0.x * QK_SCALE), (__bf16)(f0.y * QK_SCALE),
                    (__bf16)(f0.z * QK_SCALE), (__bf16)(f0.w * QK_SCALE),
                    (__bf16)(f1.x * QK_SCALE), (__bf16)(f1.y * QK_SCALE),
                    (__bf16)(f1.z * QK_SCALE), (__bf16)(f1.w * QK_SCALE)};
        *reinterpret_cast<bf16x8*>(kb + f * 512 + l * 8) = u;

        const float* vp = V + (size_t)(kv0 + r) * HD + h * HEAD_DIM + d0;
        float4 g0 = *(const float4*)vp, g1 = *(const float4*)(vp + 4);
        bf16x8 w = {(__bf16)g0.x, (__bf16)g0.y, (__bf16)g0.z, (__bf16)g0.w,
                    (__bf16)g1.x, (__bf16)g1.y, (__bf16)g1.z, (__bf16)g1.w};
        *reinterpret_cast<bf16x8*>(&v_s[r][d0]) = w;
    }
    __syncthreads();
    #pragma unroll
    for (int i = 0; i < 2; ++i) {
        const int c2 = tid + 256 * i;
        const int f  = c2 >> 6;
        const int l  = c2 & 63;
        const int g  = l >> 4, aa = l & 15;
        const int dt = f >> 1, cc = f & 1;
        const int d  = 16 * dt + aa;
        bf16x8 w;
        #pragma unroll
        for (int e = 0; e < 8; ++e) {
            const int kvl = 32 * cc + ((e >> 2) << 4) + 4 * g + (e & 3);
            w[e] = v_s[kvl][d];
        }
        *reinterpret_cast<bf16x8*>(vt + f * 512 + l * 8) = w;
    }
}

// --- attention: pair-barrier schedule — 8 barriers total (one per 2 tiles),
// --- 4 pair-buffers (128 KB dynamic LDS), counted vmcnt, drain-free lgkm,
// --- cross-tile PV(t-1) pipeline. 512 threads, QR=32/wave, 1 block/CU. ---
__global__ __launch_bounds__(512, 1)
void fattn19_kernel(const float* __restrict__ Q, const __bf16* __restrict__ ws,
                    float* __restrict__ O)
{
    extern __shared__ __bf16 lds[];   // 4 pairs x 32 KB: [tile0 K|V][tile1 K|V]

    const int tid  = threadIdx.x;
    const int lane = tid & 63;
    const int wave = tid >> 6;              // 0..7
    const int g    = lane >> 4;
    const int a    = lane & 15;

    // 256 blocks; bijective XCD chunking: XCD x gets orig in [x*32, x*32+32)
    const int b     = blockIdx.x;
    const int orig  = (b & 7) * 32 + (b >> 3);
    const int group = orig >> 2;          // h*4 + seq
    const int qb    = orig & 3;           // q-block within sequence (256 rows)
    const int h     = group >> 2;
    const int seq   = group & 3;
    const int q0    = seq * SEQL + qb * 256;   // block: 256 q rows; wave: 32

    const __bf16* kb_base = ws + (size_t)h * HSTRIDE + (size_t)seq * NTILE * TILE_E;
    const __bf16* vt_base = ws + VT_OFF + (size_t)h * HSTRIDE + (size_t)seq * NTILE * TILE_E;

    // Q fragments for 2 q-subtiles (scale folded into K by prep)
    bf16x8 qf[2][2];
    #pragma unroll
    for (int u = 0; u < 2; ++u) {
        const float* qp = Q + (size_t)(q0 + wave * 32 + u * 16 + a) * HD + h * HEAD_DIM + g * 8;
        #pragma unroll
        for (int c = 0; c < 2; ++c) {
            float4 f0 = *reinterpret_cast<const float4*>(qp + 32 * c);
            float4 f1 = *reinterpret_cast<const float4*>(qp + 32 * c + 4);
            qf[u][c][0] = (__bf16)f0.x; qf[u][c][1] = (__bf16)f0.y;
            qf[u][c][2] = (__bf16)f0.z; qf[u][c][3] = (__bf16)f0.w;
            qf[u][c][4] = (__bf16)f1.x; qf[u][c][5] = (__bf16)f1.y;
            qf[u][c][6] = (__bf16)f1.z; qf[u][c][7] = (__bf16)f1.w;
        }
    }

    f32x4 o_acc[2][4];
    #pragma unroll
    for (int u = 0; u < 2; ++u)
        #pragma unroll
        for (int dt = 0; dt < 4; ++dt) o_acc[u][dt] = (f32x4){0.f, 0.f, 0.f, 0.f};
    f32x4 l_acc[2] = {(f32x4){0.f, 0.f, 0.f, 0.f}, (f32x4){0.f, 0.f, 0.f, 0.f}};

    bf16x8 ones;
    #pragma unroll
    for (int e = 0; e < 8; ++e) ones[e] = (__bf16)1.0f;

    const f32x4 minit = (f32x4){-FIXED_M, -FIXED_M, -FIXED_M, -FIXED_M};
    const int lb    = lane * 16;   // byte slot within a 1KB fragment
    const int stid8 = tid * 8;     // 512 threads x 8 elems = one 8KB tile per inst

    // stage one pair (tiles 2p, 2p+1): 4 gload_lds per wave (vmcnt += 4)
    auto stage_pair = [&](int p) {
        __bf16* base = lds + (size_t)(p & 3) * (4 * TILE_E);
        const __bf16* ks0 = kb_base + (size_t)(2 * p)     * TILE_E + stid8;
        const __bf16* ks1 = kb_base + (size_t)(2 * p + 1) * TILE_E + stid8;
        const __bf16* vs0 = vt_base + (size_t)(2 * p)     * TILE_E + stid8;
        const __bf16* vs1 = vt_base + (size_t)(2 * p + 1) * TILE_E + stid8;
        GLOAD_LDS16(ks0, base + stid8);
        GLOAD_LDS16(vs0, base + TILE_E + stid8);
        GLOAD_LDS16(ks1, base + 2 * TILE_E + stid8);
        GLOAD_LDS16(vs1, base + 3 * TILE_E + stid8);
    };

    // PV cluster for tile t-1 (register-only MFMA; compiler's counted lgkm wait
    // drains vfP right before first use — the drain that frees the buffer)
    auto pv = [&](const bf16x8 (&pfP)[2][2], const bf16x8 (&vfP)[8]) {
        __builtin_amdgcn_s_setprio(1);
        l_acc[0] = MFMA16(pfP[0][0], ones, l_acc[0]);
        l_acc[0] = MFMA16(pfP[0][1], ones, l_acc[0]);
        l_acc[1] = MFMA16(pfP[1][0], ones, l_acc[1]);
        l_acc[1] = MFMA16(pfP[1][1], ones, l_acc[1]);
        #pragma unroll
        for (int dt = 0; dt < 4; ++dt)
            #pragma unroll
            for (int u = 0; u < 2; ++u) {
                o_acc[u][dt] = MFMA16(pfP[u][0], vfP[2 * dt],     o_acc[u][dt]);
                o_acc[u][dt] = MFMA16(pfP[u][1], vfP[2 * dt + 1], o_acc[u][dt]);
            }
        __builtin_amdgcn_s_setprio(0);
    };

    bf16x8 pfA[2][2], pfB[2][2];
    bf16x8 vfA[8], vfB[8];

    // body(t): K-reads(t) || PV(t-1) -> QK(t) -> V-reads(t) || exp(t). No drains.
    auto body = [&](int t, bf16x8 (&pfC)[2][2], bf16x8 (&vfC)[8],
                    bf16x8 (&pfP)[2][2], bf16x8 (&vfP)[8]) {
        const char* kc = (const char*)lds +
                         (size_t)((t >> 1) & 3) * 32768 + (size_t)(t & 1) * 16384;
        const char* vc = kc + 8192;

        bf16x8 kf[8];
        #pragma unroll
        for (int f = 0; f < 8; ++f)
            kf[f] = *reinterpret_cast<const bf16x8*>(kc + f * 1024 + lb);

        if (t > 0) pv(pfP, vfP);   // MFMA pipe fills K ds_read latency; drains vf(t-1)

        // ---- QK^T (swapped): s[u][q4][r] = S^T[kv=16q4+4g+r][q=a] - FIXED_M ----
        f32x4 s[2][4];
        __builtin_amdgcn_s_setprio(1);
        #pragma unroll
        for (int q4 = 0; q4 < 4; ++q4) {
            s[0][q4] = MFMA16(kf[2 * q4],     qf[0][0], minit);
            s[0][q4] = MFMA16(kf[2 * q4 + 1], qf[0][1], s[0][q4]);
            s[1][q4] = MFMA16(kf[2 * q4],     qf[1][0], minit);
            s[1][q4] = MFMA16(kf[2 * q4 + 1], qf[1][1], s[1][q4]);
        }
        __builtin_amdgcn_s_setprio(0);

        // V fragment reads; drain lazily under the next body's PV lgkm wait
        #pragma unroll
        for (int f = 0; f < 8; ++f)
            vfC[f] = *reinterpret_cast<const bf16x8*>(vc + f * 1024 + lb);

        // fixed-shift softmax: pf[u][c] elem bb -> kv = 32c + 16(bb>>2) + 4g + (bb&3)
        #pragma unroll
        for (int u = 0; u < 2; ++u)
            #pragma unroll
            for (int c = 0; c < 2; ++c)
                #pragma unroll
                for (int bb = 0; bb < 8; ++bb)
                    pfC[u][c][bb] = (__bf16)__builtin_amdgcn_exp2f(s[u][2 * c + (bb >> 2)][bb & 3]);
    };

    stage_pair(0);
    stage_pair(1);   // 8 vm outstanding

    // 8 phases, one barrier each. Pair p's buffer is overwritten at phase p+2; its vf
    // reads are drained by PV(2p+1)'s lgkm wait in body 2p+2 (phase p+1) — safe.
    #pragma unroll
    for (int p = 0; p < 8; ++p) {
        if (p == 7) asm volatile("s_waitcnt vmcnt(0)" ::: "memory");
        else        asm volatile("s_waitcnt vmcnt(4)" ::: "memory");
        __builtin_amdgcn_sched_barrier(0);
        __builtin_amdgcn_s_barrier();
        __builtin_amdgcn_sched_barrier(0);   // no ds_read hoisted above the barrier
        if (p <= 5) stage_pair(p + 2);

        body(2 * p,     pfA, vfA, pfB, vfB);
        body(2 * p + 1, pfB, vfB, pfA, vfA);
    }
    pv(pfB, vfB);   // PV(15)

    // ---- epilogue: O rows q = wave*32 + u*16 + 4g + r, cols d = 16dt + a ----
    #pragma unroll
    for (int u = 0; u < 2; ++u)
        #pragma unroll
        for (int r = 0; r < 4; ++r) {
            const float inv = 1.0f / l_acc[u][r];
            float* op = O + (size_t)(q0 + wave * 32 + u * 16 + 4 * g + r) * HD + h * HEAD_DIM + a;
            #pragma unroll
            for (int dt = 0; dt < 4; ++dt)
                op[16 * dt] = o_acc[u][dt][r] * inv;
        }
}

extern "C" void kernel_launch(void* const* d_in, const int* in_sizes, int n_in,
                              void* d_out, int out_size, void* d_ws, size_t ws_size,
                              hipStream_t stream) {
    const float* q = (const float*)d_in[0];
    const float* k = (const float*)d_in[1];
    const float* v = (const float*)d_in[2];
    float* out = (float*)d_out;
    __bf16* ws = (__bf16*)d_ws;   // 16 MB: 8 MB K-fragments (pre-scaled) + 8 MB V-fragments

    // allow 128 KB dynamic LDS (idempotent, deterministic; not a stream op)
    hipFuncSetAttribute((const void*)fattn19_kernel,
                        hipFuncAttributeMaxDynamicSharedMemorySize, 4 * 4 * TILE_E * 2);

    prep_kernel<<<1024, 256, 0, stream>>>(k, v, ws);
    fattn19_kernel<<<256, 512, 4 * 4 * TILE_E * 2, stream>>>(q, ws, out);
}